// Round 1
// baseline (180.502 us; speedup 1.0000x reference)
//
#include <hip/hip_runtime.h>
#include <hip/hip_bf16.h>
#include <cstdint>
#include <math.h>

#define NB 4
#define NN 512
#define DH 128
#define NHEADS 8
#define NHID 16
#define SLOPE 0.2f
#define ITILE 32
#define SENTINEL -1e30f

// ---- one-time adjacency bitmask pack: adjb[row][w] bit k = adj[row][w*32+k] ----
__global__ __launch_bounds__(256) void pack_adj_kernel(
    const int* __restrict__ adj, uint32_t* __restrict__ adjb)
{
    const int t   = threadIdx.x;
    const int row = blockIdx.x * 16 + (t >> 4);
    const int w   = t & 15;
    const int4* p = (const int4*)(adj + (size_t)row * NN + w * 32);
    uint32_t m = 0;
#pragma unroll
    for (int c = 0; c < 8; ++c) {
        const int4 v = p[c];
        m |= (v.x != 0 ? 1u : 0u) << (c * 4 + 0);
        m |= (v.y != 0 ? 1u : 0u) << (c * 4 + 1);
        m |= (v.z != 0 ? 1u : 0u) << (c * 4 + 2);
        m |= (v.w != 0 ? 1u : 0u) << (c * 4 + 3);
    }
    adjb[(size_t)row * 16 + w] = m;
}

// ---- projection: 8 rows/block, outputs HEAD-MAJOR gl/gr [b*8+hh][512][16] ----
__global__ __launch_bounds__(256) void proj_kernel(
    const float* __restrict__ h, const float* __restrict__ X,
    const float* __restrict__ Win,
    const float* __restrict__ Wl, const float* __restrict__ Wr,
    float* __restrict__ gl, float* __restrict__ gr)
{
    __shared__ __align__(16) float s_h[8][DH];
    const int bn0 = blockIdx.x * 8;
    const int b   = bn0 >> 9;
    const int n0  = bn0 & 511;
    const int t   = threadIdx.x;

    if (X) {
        if (t < DH) {
            const float w0 = Win[t], w1 = Win[DH + t];
#pragma unroll
            for (int r = 0; r < 8; ++r) {
                const float x0 = X[(bn0 + r) * 2 + 0];
                const float x1 = X[(bn0 + r) * 2 + 1];
                s_h[r][t] = x0 * w0 + x1 * w1;
            }
        }
    } else {
        for (int idx = t; idx < 8 * DH; idx += 256)
            s_h[idx >> 7][idx & 127] = h[(size_t)bn0 * DH + idx];
    }
    __syncthreads();

    const float* W = (t < DH) ? Wl : Wr;   // wave-uniform split
    float*       g = (t < DH) ? gl : gr;
    const int f128 = t & 127;
    float acc[8] = {};
    for (int k = 0; k < DH; k += 4) {
        const float w0 = W[(k + 0) * DH + f128];
        const float w1 = W[(k + 1) * DH + f128];
        const float w2 = W[(k + 2) * DH + f128];
        const float w3 = W[(k + 3) * DH + f128];
#pragma unroll
        for (int r = 0; r < 8; ++r) {
            const float4 hv = *(const float4*)&s_h[r][k];
            acc[r] += hv.x * w0 + hv.y * w1 + hv.z * w2 + hv.w * w3;
        }
    }
    const int hh = f128 >> 4, f = f128 & 15;
    float* dst = g + ((size_t)(b * NHEADS + hh) * NN + n0) * NHID + f;
#pragma unroll
    for (int r = 0; r < 8; ++r)
        dst[r * NHID] = acc[r];
}

// ---- flash-style attention: one block per (b, head, 32-row i-tile) ----
// 512 threads: il = t&31 (query row), js = t>>5 (32-j slice).
// gl/gr head slices staged in LDS (64KB); main loop j is wave-uniform
// (2 addrs/wave -> broadcast, free). Online softmax in registers,
// sentinel -1e30 self-heals all-masked prefixes (self-loops guarantee
// every row has >=1 valid edge). Merge scratch aliases dead gl/gr.
__global__ __launch_bounds__(512) void attn_kernel(
    const float* __restrict__ gl, const float* __restrict__ gr,
    const uint32_t* __restrict__ adjb, const float* __restrict__ a_vec,
    float* __restrict__ h_out,
    const float* __restrict__ Wout, float* __restrict__ out)
{
    __shared__ __align__(16) float smem[17504];     // 70016 B -> 2 blocks/CU
    float* s_gl  = smem;                // [512*16]
    float* s_gr  = smem + 8192;         // [512*16]
    float* s_acc = smem;                // alias (dead gl/gr), [16*32*17]=8704
    float* s_m   = smem + 16384;        // [16*33]
    float* s_l   = smem + 16912;        // [16*33]
    float* s_M   = smem + 17440;        // [32]
    float* s_inv = smem + 17472;        // [32]

    const int blk = blockIdx.x;         // 512 = (b*8+hh)*16 + it
    const int it  = blk & 15;
    const int bh  = blk >> 4;
    const int b   = bh >> 3;
    const int hh  = bh & 7;
    const int i0  = it * ITILE;
    const int t   = threadIdx.x;
    const int il  = t & 31;
    const int js  = t >> 5;

    {   // stage head planes: contiguous 32KB each, fully coalesced
        const float4* pgl = (const float4*)(gl + (size_t)bh * NN * NHID);
        const float4* pgr = (const float4*)(gr + (size_t)bh * NN * NHID);
        float4* dl = (float4*)s_gl;
        float4* dr = (float4*)s_gr;
#pragma unroll
        for (int k = 0; k < 4; ++k) {
            dl[k * 512 + t] = pgl[k * 512 + t];
            dr[k * 512 + t] = pgr[k * 512 + t];
        }
    }
    float a[16];
    {
        const float4* pa = (const float4*)a_vec;
#pragma unroll
        for (int q = 0; q < 4; ++q) {
            const float4 v = pa[q];
            a[4*q] = v.x; a[4*q+1] = v.y; a[4*q+2] = v.z; a[4*q+3] = v.w;
        }
    }
    const uint32_t mask = adjb[((size_t)(b * NN + i0 + il)) * 16 + js];
    __syncthreads();

    float gri[16];
    {
        const float4* pr = (const float4*)(s_gr + (i0 + il) * NHID);
#pragma unroll
        for (int q = 0; q < 4; ++q) {
            const float4 v = pr[q];
            gri[4*q] = v.x; gri[4*q+1] = v.y; gri[4*q+2] = v.z; gri[4*q+3] = v.w;
        }
    }

    float m = SENTINEL, l = 0.f;
    float acc[16];
#pragma unroll
    for (int f = 0; f < 16; ++f) acc[f] = 0.f;

    const int jbase = js * 32;
    for (int jc = 0; jc < 32; jc += 4) {
        float sc[4];
#pragma unroll
        for (int k = 0; k < 4; ++k) {
            const int jj = jc + k;
            const float4* pg = (const float4*)(s_gl + (jbase + jj) * NHID);
            float s = 0.f;
#pragma unroll
            for (int q = 0; q < 4; ++q) {
                const float4 g = pg[q];     // wave-uniform j -> broadcast
                float v;
                v = g.x + gri[4*q+0]; v = fmaxf(v, SLOPE * v); s += v * a[4*q+0];
                v = g.y + gri[4*q+1]; v = fmaxf(v, SLOPE * v); s += v * a[4*q+1];
                v = g.z + gri[4*q+2]; v = fmaxf(v, SLOPE * v); s += v * a[4*q+2];
                v = g.w + gri[4*q+3]; v = fmaxf(v, SLOPE * v); s += v * a[4*q+3];
            }
            sc[k] = ((mask >> jj) & 1u) ? s : SENTINEL;
        }
        const float m4   = fmaxf(fmaxf(sc[0], sc[1]), fmaxf(sc[2], sc[3]));
        const float newm = fmaxf(m, m4);
        const float corr = __expf(m - newm);    // ==1 when no new max
        l *= corr;
#pragma unroll
        for (int f = 0; f < 16; ++f) acc[f] *= corr;
        float p[4];
#pragma unroll
        for (int k = 0; k < 4; ++k) p[k] = __expf(sc[k] - newm);  // masked -> 0
        l += p[0] + p[1] + p[2] + p[3];
#pragma unroll
        for (int k = 0; k < 4; ++k) {
            const float4* pg = (const float4*)(s_gr + (jbase + jc + k) * NHID);
#pragma unroll
            for (int q = 0; q < 4; ++q) {
                const float4 g = pg[q];     // broadcast
                acc[4*q+0] += p[k] * g.x; acc[4*q+1] += p[k] * g.y;
                acc[4*q+2] += p[k] * g.z; acc[4*q+3] += p[k] * g.w;
            }
        }
        m = newm;
    }

    s_m[js * 33 + il] = m;
    s_l[js * 33 + il] = l;
    __syncthreads();                     // also retires all gl/gr LDS reads

    if (t < 32) {                        // per-i global max + denom
        float M = SENTINEL;
#pragma unroll
        for (int k = 0; k < 16; ++k) M = fmaxf(M, s_m[k * 33 + t]);
        float L = 0.f;
#pragma unroll
        for (int k = 0; k < 16; ++k) L += s_l[k * 33 + t] * __expf(s_m[k * 33 + t] - M);
        s_M[t]   = M;
        s_inv[t] = 1.f / L;
    }
    __syncthreads();

    {   // scaled partials into aliased scratch (stride 17 -> conflict-free)
        const float scale = __expf(m - s_M[il]) * s_inv[il];
        float* dst = s_acc + (js * 32 + il) * 17;
#pragma unroll
        for (int f = 0; f < 16; ++f) dst[f] = acc[f] * scale;
    }
    __syncthreads();

    {   // final reduce: thread (i = t>>4, f = t&15)
        const int i = t >> 4, f = t & 15;
        float o = 0.f;
#pragma unroll
        for (int k = 0; k < 16; ++k) o += s_acc[(k * 32 + i) * 17 + f];
        if (Wout) {                      // fused h @ W_out partial per head
            float v = o * Wout[hh * NHID + f];
#pragma unroll
            for (int off = 8; off; off >>= 1) v += __shfl_xor(v, off);
            if (f == 0) atomicAdd(out + b * NN + i0 + i, v);
        } else {
            h_out[((size_t)(b * NN + i0 + i)) * DH + hh * NHID + f] = o;
        }
    }
}

extern "C" void kernel_launch(void* const* d_in, const int* in_sizes, int n_in,
                              void* d_out, int out_size, void* d_ws, size_t ws_size,
                              hipStream_t stream) {
    const float* X    = (const float*)d_in[0];   // [4,512,2]
    const int*   adj  = (const int*)  d_in[1];   // [4,512,512]
    const float* Win  = (const float*)d_in[2];   // [2,128]
    const float* Wl   = (const float*)d_in[3];   // [3,128,128]
    const float* Wr   = (const float*)d_in[4];   // [3,128,128]
    const float* Aa   = (const float*)d_in[5];   // [3,16]
    const float* Wout = (const float*)d_in[6];   // [128,1]
    float* out = (float*)d_out;                  // [4,512] fp32

    float*    ws   = (float*)d_ws;
    float*    h    = ws;                 // 1 MB
    float*    gl   = ws + 262144;        // 1 MB (head-major)
    float*    gr   = ws + 524288;        // 1 MB (head-major)
    uint32_t* adjb = (uint32_t*)(ws + 786432);   // 128 KB

    pack_adj_kernel<<<NB * NN / 16, 256, 0, stream>>>(adj, adjb);
    hipMemsetAsync(out, 0, (size_t)out_size * sizeof(float), stream);  // atomic target

    for (int l = 0; l < 3; ++l) {
        proj_kernel<<<NB * NN / 8, 256, 0, stream>>>(
            h, (l == 0) ? X : nullptr, Win,
            Wl + (size_t)l * DH * DH, Wr + (size_t)l * DH * DH, gl, gr);
        const bool last = (l == 2);
        attn_kernel<<<NB * NHEADS * (NN / ITILE), 512, 0, stream>>>(
            gl, gr, adjb, Aa + l * NHID, h,
            last ? Wout : nullptr, out);
    }
}

// Round 2
// 161.040 us; speedup vs baseline: 1.1208x; 1.1208x over previous
//
#include <hip/hip_runtime.h>
#include <cstdint>
#include <math.h>

#define NB 4
#define NN 512
#define DH 128
#define NHEADS 8
#define NHID 16
#define SLOPE 0.2f
#define ITILE 64
#define SENTINEL -1e30f

// ---- one-time adjacency bitmask pack: adjb[row][w] bit k = adj[row][w*32+k] ----
__global__ __launch_bounds__(256) void pack_adj_kernel(
    const int* __restrict__ adj, uint32_t* __restrict__ adjb)
{
    const int t   = threadIdx.x;
    const int row = blockIdx.x * 16 + (t >> 4);
    const int w   = t & 15;
    const int4* p = (const int4*)(adj + (size_t)row * NN + w * 32);
    uint32_t m = 0;
#pragma unroll
    for (int c = 0; c < 8; ++c) {
        const int4 v = p[c];
        m |= (v.x != 0 ? 1u : 0u) << (c * 4 + 0);
        m |= (v.y != 0 ? 1u : 0u) << (c * 4 + 1);
        m |= (v.z != 0 ? 1u : 0u) << (c * 4 + 2);
        m |= (v.w != 0 ? 1u : 0u) << (c * 4 + 3);
    }
    adjb[(size_t)row * 16 + w] = m;
}

// ---- projection: 8 rows/block, outputs HEAD-MAJOR gl/gr [b*8+hh][512][16] ----
__global__ __launch_bounds__(256) void proj_kernel(
    const float* __restrict__ h, const float* __restrict__ X,
    const float* __restrict__ Win,
    const float* __restrict__ Wl, const float* __restrict__ Wr,
    float* __restrict__ gl, float* __restrict__ gr)
{
    __shared__ __align__(16) float s_h[8][DH];
    const int bn0 = blockIdx.x * 8;
    const int b   = bn0 >> 9;
    const int n0  = bn0 & 511;
    const int t   = threadIdx.x;

    if (X) {
        if (t < DH) {
            const float w0 = Win[t], w1 = Win[DH + t];
#pragma unroll
            for (int r = 0; r < 8; ++r) {
                const float x0 = X[(bn0 + r) * 2 + 0];
                const float x1 = X[(bn0 + r) * 2 + 1];
                s_h[r][t] = x0 * w0 + x1 * w1;
            }
        }
    } else {
        for (int idx = t; idx < 8 * DH; idx += 256)
            s_h[idx >> 7][idx & 127] = h[(size_t)bn0 * DH + idx];
    }
    __syncthreads();

    const float* W = (t < DH) ? Wl : Wr;   // wave-uniform split
    float*       g = (t < DH) ? gl : gr;
    const int f128 = t & 127;
    float acc[8] = {};
    for (int k = 0; k < DH; k += 4) {
        const float w0 = W[(k + 0) * DH + f128];
        const float w1 = W[(k + 1) * DH + f128];
        const float w2 = W[(k + 2) * DH + f128];
        const float w3 = W[(k + 3) * DH + f128];
#pragma unroll
        for (int r = 0; r < 8; ++r) {
            const float4 hv = *(const float4*)&s_h[r][k];
            acc[r] += hv.x * w0 + hv.y * w1 + hv.z * w2 + hv.w * w3;
        }
    }
    const int hh = f128 >> 4, f = f128 & 15;
    float* dst = g + ((size_t)(b * NHEADS + hh) * NN + n0) * NHID + f;
#pragma unroll
    for (int r = 0; r < 8; ++r)
        dst[r * NHID] = acc[r];
}

// ---- attention v2: one block per (b, head, 64-row i-tile), 2 rows/thread ----
// 512 threads: il = t&31 -> rows (i0+il, i0+il+32); js = t>>5 -> 32-j slice.
// Halves ds_read_b128 per (i,j) pair vs v1 (each gl/gr row read feeds 2 rows).
// Score factored via lrelu(x) = 0.6x + 0.4|x|:
//   e(i,j) = 0.6*(dgl[j]+dgr[i]) + 0.4*sum_f a_f*|gl[j,f]+gr[i,f]|
// with dgl/dgr (a . row) computed once from staging registers (quad shuffle).
// Two-pass in-register softmax (sc[2][32]); grid 256 = 1 block/CU so VGPR
// budget is 256 (launch_bounds 512,2). Sentinel -1e30 self-heals all-masked
// slices: scale = exp(m - M) -> 0 exactly.
__global__ __launch_bounds__(512, 2) void attn_kernel(
    const float* __restrict__ gl, const float* __restrict__ gr,
    const uint32_t* __restrict__ adjb, const float* __restrict__ a_vec,
    float* __restrict__ h_out,
    const float* __restrict__ Wout, float* __restrict__ out)
{
    __shared__ __align__(16) float smem[19616];     // 78464 B
    float* s_gl  = smem;                 // [512][16]
    float* s_gr  = smem + 8192;          // [512][16]
    float* s_acc = smem;                 // alias (post-pass): [16][64][16] swizzled
    float* s_dgl = smem + 16384;         // [512]
    float* s_dgr = smem + 16896;         // [512]
    float* s_m   = smem + 17408;         // [16][65]
    float* s_l   = smem + 18448;         // [16][65]
    float* s_M   = smem + 19488;         // [64]
    float* s_inv = smem + 19552;         // [64]

    const int blk = blockIdx.x;          // 256 = bh*8 + it
    const int it  = blk & 7;
    const int bh  = blk >> 3;
    const int b   = bh >> 3;
    const int hh  = bh & 7;
    const int i0  = it * ITILE;
    const int t   = threadIdx.x;
    const int il  = t & 31;
    const int js  = t >> 5;              // [0,16)
    const int r0  = i0 + il;             // plane-local rows
    const int r1  = r0 + 32;

    // ---- stage head planes; keep copies in regs for dgl/dgr dots ----
    const float4* pgl = (const float4*)(gl + (size_t)bh * NN * NHID);
    const float4* pgr = (const float4*)(gr + (size_t)bh * NN * NHID);
    float4 rl[4], rr[4];
#pragma unroll
    for (int k = 0; k < 4; ++k) { rl[k] = pgl[k * 512 + t]; rr[k] = pgr[k * 512 + t]; }

    const uint32_t mask0 = adjb[((size_t)(b * NN + r0)) * 16 + js];
    const uint32_t mask1 = adjb[((size_t)(b * NN + r1)) * 16 + js];

    // gri from GLOBAL (L2-hot; LDS row-gather would be a 32-way bank conflict)
    float gri0[16], gri1[16];
#pragma unroll
    for (int q = 0; q < 4; ++q) {
        const float4 v0 = pgr[r0 * 4 + q];
        const float4 v1 = pgr[r1 * 4 + q];
        gri0[4*q+0] = v0.x; gri0[4*q+1] = v0.y; gri0[4*q+2] = v0.z; gri0[4*q+3] = v0.w;
        gri1[4*q+0] = v1.x; gri1[4*q+1] = v1.y; gri1[4*q+2] = v1.z; gri1[4*q+3] = v1.w;
    }

    float a[16];   // uniform addr -> s_load -> SGPRs
#pragma unroll
    for (int q = 0; q < 4; ++q) {
        const float4 v = ((const float4*)a_vec)[q];
        a[4*q+0] = v.x; a[4*q+1] = v.y; a[4*q+2] = v.z; a[4*q+3] = v.w;
    }

    {   // LDS stores of the staged planes
        float4* dl = (float4*)s_gl;
        float4* dr = (float4*)s_gr;
#pragma unroll
        for (int k = 0; k < 4; ++k) { dl[k * 512 + t] = rl[k]; dr[k * 512 + t] = rr[k]; }
    }

    {   // dgl[j] = a . gl[j], dgr[j] = a . gr[j] from staging regs (quad reduce)
        const float4 aq = ((const float4*)a_vec)[t & 3];
#pragma unroll
        for (int k = 0; k < 4; ++k) {
            float pl = rl[k].x * aq.x + rl[k].y * aq.y + rl[k].z * aq.z + rl[k].w * aq.w;
            float pr = rr[k].x * aq.x + rr[k].y * aq.y + rr[k].z * aq.z + rr[k].w * aq.w;
            pl += __shfl_xor(pl, 1); pl += __shfl_xor(pl, 2);
            pr += __shfl_xor(pr, 1); pr += __shfl_xor(pr, 2);
            if ((t & 3) == 0) {
                const int row = k * 128 + (t >> 2);
                s_dgl[row] = pl;
                s_dgr[row] = pr;
            }
        }
    }
    __syncthreads();

    // ---- pass 1: scores for 2 rows x 32 j ----
    const float c0 = 0.6f * s_dgr[r0];
    const float c1 = 0.6f * s_dgr[r1];
    const int jbase = js * 32;
    float sc0[32], sc1[32];
#pragma unroll
    for (int jj = 0; jj < 32; ++jj) {
        const int j = jbase + jj;
        const float4* pg = (const float4*)(s_gl + j * NHID);
        const float dj = s_dgl[j];
        float s0 = 0.f, s1 = 0.f;
#pragma unroll
        for (int q = 0; q < 4; ++q) {
            const float4 g = pg[q];     // 2 addrs/wave -> broadcast
            float v;
            v = g.x + gri0[4*q+0]; s0 = fmaf(a[4*q+0], fabsf(v), s0);
            v = g.y + gri0[4*q+1]; s0 = fmaf(a[4*q+1], fabsf(v), s0);
            v = g.z + gri0[4*q+2]; s0 = fmaf(a[4*q+2], fabsf(v), s0);
            v = g.w + gri0[4*q+3]; s0 = fmaf(a[4*q+3], fabsf(v), s0);
            v = g.x + gri1[4*q+0]; s1 = fmaf(a[4*q+0], fabsf(v), s1);
            v = g.y + gri1[4*q+1]; s1 = fmaf(a[4*q+1], fabsf(v), s1);
            v = g.z + gri1[4*q+2]; s1 = fmaf(a[4*q+2], fabsf(v), s1);
            v = g.w + gri1[4*q+3]; s1 = fmaf(a[4*q+3], fabsf(v), s1);
        }
        const float b0 = fmaf(0.6f, dj, c0);
        const float b1 = fmaf(0.6f, dj, c1);
        sc0[jj] = ((mask0 >> jj) & 1u) ? fmaf(0.4f, s0, b0) : SENTINEL;
        sc1[jj] = ((mask1 >> jj) & 1u) ? fmaf(0.4f, s1, b1) : SENTINEL;
    }

    // ---- in-register softmax (two-pass, no online rescale) ----
    float m0 = sc0[0], m1 = sc1[0];
#pragma unroll
    for (int jj = 1; jj < 32; ++jj) { m0 = fmaxf(m0, sc0[jj]); m1 = fmaxf(m1, sc1[jj]); }
    float l0 = 0.f, l1 = 0.f;
#pragma unroll
    for (int jj = 0; jj < 32; ++jj) {
        sc0[jj] = __expf(sc0[jj] - m0); l0 += sc0[jj];
        sc1[jj] = __expf(sc1[jj] - m1); l1 += sc1[jj];
    }
    s_m[js * 65 + il]      = m0;
    s_m[js * 65 + il + 32] = m1;
    s_l[js * 65 + il]      = l0;
    s_l[js * 65 + il + 32] = l1;

    // ---- pass 2: PV aggregation ----
    float acc0[16], acc1[16];
#pragma unroll
    for (int f = 0; f < 16; ++f) { acc0[f] = 0.f; acc1[f] = 0.f; }
#pragma unroll
    for (int jj = 0; jj < 32; ++jj) {
        const float4* pg = (const float4*)(s_gr + (jbase + jj) * NHID);
        const float p0 = sc0[jj], p1 = sc1[jj];
#pragma unroll
        for (int q = 0; q < 4; ++q) {
            const float4 g = pg[q];     // broadcast
            acc0[4*q+0] = fmaf(p0, g.x, acc0[4*q+0]);
            acc0[4*q+1] = fmaf(p0, g.y, acc0[4*q+1]);
            acc0[4*q+2] = fmaf(p0, g.z, acc0[4*q+2]);
            acc0[4*q+3] = fmaf(p0, g.w, acc0[4*q+3]);
            acc1[4*q+0] = fmaf(p1, g.x, acc1[4*q+0]);
            acc1[4*q+1] = fmaf(p1, g.y, acc1[4*q+1]);
            acc1[4*q+2] = fmaf(p1, g.z, acc1[4*q+2]);
            acc1[4*q+3] = fmaf(p1, g.w, acc1[4*q+3]);
        }
    }
    __syncthreads();                     // retires all gl/gr reads + s_m/s_l writes

    if (t < 64) {                        // per-row global max + denom over 16 slices
        float M = SENTINEL;
#pragma unroll
        for (int k = 0; k < 16; ++k) M = fmaxf(M, s_m[k * 65 + t]);
        float L = 0.f;
#pragma unroll
        for (int k = 0; k < 16; ++k) L += s_l[k * 65 + t] * __expf(s_m[k * 65 + t] - M);
        s_M[t]   = M;
        s_inv[t] = 1.f / L;
    }
    __syncthreads();

    {   // scaled partials into aliased scratch; chunk-XOR swizzle kills conflicts
        const float k0 = __expf(m0 - s_M[il])      * s_inv[il];
        const float k1 = __expf(m1 - s_M[il + 32]) * s_inv[il + 32];
        const int swz = il & 3;          // same for row il+32
        float* base_a = s_acc + js * 1024;
#pragma unroll
        for (int q = 0; q < 4; ++q) {
            float4 v0, v1;
            v0.x = acc0[4*q+0] * k0; v0.y = acc0[4*q+1] * k0;
            v0.z = acc0[4*q+2] * k0; v0.w = acc0[4*q+3] * k0;
            v1.x = acc1[4*q+0] * k1; v1.y = acc1[4*q+1] * k1;
            v1.z = acc1[4*q+2] * k1; v1.w = acc1[4*q+3] * k1;
            *(float4*)(base_a + il * 16        + 4 * (q ^ swz)) = v0;
            *(float4*)(base_a + (il + 32) * 16 + 4 * (q ^ swz)) = v1;
        }
    }
    __syncthreads();

    {   // final reduce over 16 slices: thread (i = t>>4, f = t&15), 2 rows each
        const int i  = t >> 4;
        const int f  = t & 15;
        const int e  = f & 3, qf = f >> 2;
#pragma unroll
        for (int r = 0; r < 2; ++r) {
            const int lr = i + r * 32;
            const int w  = lr * 16 + 4 * (qf ^ (lr & 3)) + e;
            float o = 0.f;
#pragma unroll
            for (int k = 0; k < 16; ++k) o += s_acc[k * 1024 + w];
            const int grow = i0 + lr;
            if (Wout) {                  // fused h @ W_out partial per head
                float v = o * Wout[hh * NHID + f];
#pragma unroll
                for (int off = 8; off; off >>= 1) v += __shfl_xor(v, off);
                if (f == 0) atomicAdd(out + b * NN + grow, v);
            } else {
                h_out[((size_t)(b * NN + grow)) * DH + hh * NHID + f] = o;
            }
        }
    }
}

extern "C" void kernel_launch(void* const* d_in, const int* in_sizes, int n_in,
                              void* d_out, int out_size, void* d_ws, size_t ws_size,
                              hipStream_t stream) {
    const float* X    = (const float*)d_in[0];   // [4,512,2]
    const int*   adj  = (const int*)  d_in[1];   // [4,512,512]
    const float* Win  = (const float*)d_in[2];   // [2,128]
    const float* Wl   = (const float*)d_in[3];   // [3,128,128]
    const float* Wr   = (const float*)d_in[4];   // [3,128,128]
    const float* Aa   = (const float*)d_in[5];   // [3,16]
    const float* Wout = (const float*)d_in[6];   // [128,1]
    float* out = (float*)d_out;                  // [4,512] fp32

    float*    ws   = (float*)d_ws;
    float*    h    = ws;                 // 1 MB
    float*    gl   = ws + 262144;        // 1 MB (head-major)
    float*    gr   = ws + 524288;        // 1 MB (head-major)
    uint32_t* adjb = (uint32_t*)(ws + 786432);   // 128 KB

    pack_adj_kernel<<<NB * NN / 16, 256, 0, stream>>>(adj, adjb);
    hipMemsetAsync(out, 0, (size_t)out_size * sizeof(float), stream);  // atomic target

    for (int l = 0; l < 3; ++l) {
        proj_kernel<<<NB * NN / 8, 256, 0, stream>>>(
            h, (l == 0) ? X : nullptr, Win,
            Wl + (size_t)l * DH * DH, Wr + (size_t)l * DH * DH, gl, gr);
        const bool last = (l == 2);
        attn_kernel<<<NB * NHEADS * (NN / ITILE), 512, 0, stream>>>(
            gl, gr, adjb, Aa + l * NHID, h,
            last ? Wout : nullptr, out);
    }
}